// Round 1
// 208.791 us; speedup vs baseline: 1.0357x; 1.0357x over previous
//
#include <hip/hip_runtime.h>
#include <hip/hip_bf16.h>

// StyleLoss — x (1,512,64,64) fp32, target (512,256,256) fp32 -> scalar loss.
// loss = mean_{i,a,b}( (g_full[(i+a)%512,(i+b)%512]/2^20 - target[i,a,b])^2 ) * 1e6
// g_full = feats @ feats^T, feats = x reshaped (512, 4096), bf16 MFMA (tol ~2%).
//
// R4: timed iteration = 2x 77us ws-poison fills (harness, uncontrollable) + ~62us
// of our kernels. Biggest controllable suspect: loss kernel's g-gather was 64
// scalar dword loads/thread (per-element &511 blocked merging). Now reduce writes
// a padded+pre-scaled g_pad[512][768] (cols 512..767 duplicate 0..255) so the
// loss reads ONE coalesced 16B load per (j,k) — 80 -> 32 VMEM instrs/thread.
//
// ws: [0,4MB) bf16 feats; [4,8MB) fp32 g_part[4][512*512];
//     [8MB,+1.5MB) fp32 g_pad[512][768]; then fp32 partials[2048].

typedef __attribute__((ext_vector_type(8))) short bf16x8;   // 8 bf16 in 4 VGPRs
typedef __attribute__((ext_vector_type(4))) float f32x4;

#define CH 512
#define KDIM 4096
#define FEATS_ELEMS (CH * KDIM)
#define SPLITK 4
#define LOSS_BLOCKS 2048
#define GPAD 768

// ---------------------------------------------------------------- convert ----
__global__ __launch_bounds__(256) void convert_kernel(const float* __restrict__ x,
                                                      __hip_bfloat16* __restrict__ feats) {
    int idx = blockIdx.x * 256 + threadIdx.x;   // 262144 threads, 8 elems each
    const float4* x4 = (const float4*)x;
    float4 v0 = x4[idx * 2 + 0];
    float4 v1 = x4[idx * 2 + 1];
    float f[8] = {v0.x, v0.y, v0.z, v0.w, v1.x, v1.y, v1.z, v1.w};
    union { ushort u[8]; uint4 v; } o;
#pragma unroll
    for (int i = 0; i < 8; ++i) {
        __hip_bfloat16 b = __float2bfloat16(f[i]);
        o.u[i] = *reinterpret_cast<ushort*>(&b);
    }
    *reinterpret_cast<uint4*>(feats + idx * 8) = o.v;
}

// ---------------------------------------------------------------- gemm -------
// C = F * F^T, F 512x4096 bf16 row-major. 64x64 tile, BK=64, split-K=4
// (256 blocks), register prefetch, plain stores into private slice g_part[kz].
#define BM 64
#define BK 64
#define LDT 72   // padded LDS stride in bf16: 144 B (b128-aligned, 2-way alias = free)

__global__ __launch_bounds__(256) void gemm_kernel(const __hip_bfloat16* __restrict__ feats,
                                                   float* __restrict__ g_part) {
    __shared__ __hip_bfloat16 a_tile[BM * LDT];
    __shared__ __hip_bfloat16 b_tile[BM * LDT];

    const int bm = blockIdx.x, bn = blockIdx.y, kz = blockIdx.z;
    const int tid  = threadIdx.x;
    const int lane = tid & 63;
    const int w    = tid >> 6;        // wave 0..3 -> M rows w*16..w*16+15
    const int m    = lane & 15;
    const int q    = lane >> 4;       // quad: k offset q*8

    const int srow = tid >> 3;        // staging row 0..31 (+32 for p=1)
    const int scol = (tid & 7) * 8;   // 0..56 step 8

    f32x4 acc[4] = {};                // 4 N-subtiles of 16 cols

    const int NT = (KDIM / SPLITK) / BK;            // 16 k-tiles per block
    const int k0base = kz * (KDIM / SPLITK);        // 1024 per split

    const __hip_bfloat16* arow0 = feats + (size_t)(bm * 64 + srow) * KDIM + k0base + scol;
    const __hip_bfloat16* brow0 = feats + (size_t)(bn * 64 + srow) * KDIM + k0base + scol;

    uint4 pa[2], pb[2];
#pragma unroll
    for (int p = 0; p < 2; ++p) {
        pa[p] = *(const uint4*)(arow0 + (size_t)p * 32 * KDIM);
        pb[p] = *(const uint4*)(brow0 + (size_t)p * 32 * KDIM);
    }

    for (int kt = 0; kt < NT; ++kt) {
        if (kt > 0) __syncthreads();               // previous MFMA reads done
#pragma unroll
        for (int p = 0; p < 2; ++p) {
            uint* ap = (uint*)(a_tile + (srow + p * 32) * LDT + scol);
            ap[0] = pa[p].x; ap[1] = pa[p].y; ap[2] = pa[p].z; ap[3] = pa[p].w;
            uint* bp = (uint*)(b_tile + (srow + p * 32) * LDT + scol);
            bp[0] = pb[p].x; bp[1] = pb[p].y; bp[2] = pb[p].z; bp[3] = pb[p].w;
        }
        __syncthreads();
        if (kt + 1 < NT) {                         // prefetch next tile (overlaps MFMA)
            const int ko = (kt + 1) * BK;
#pragma unroll
            for (int p = 0; p < 2; ++p) {
                pa[p] = *(const uint4*)(arow0 + (size_t)p * 32 * KDIM + ko);
                pb[p] = *(const uint4*)(brow0 + (size_t)p * 32 * KDIM + ko);
            }
        }
#pragma unroll
        for (int ks = 0; ks < 2; ++ks) {
            const int kk = ks * 32 + q * 8;
            bf16x8 afrag = *(const bf16x8*)(a_tile + (w * 16 + m) * LDT + kk);
#pragma unroll
            for (int j = 0; j < 4; ++j) {
                bf16x8 bfrag = *(const bf16x8*)(b_tile + (j * 16 + m) * LDT + kk);
                acc[j] = __builtin_amdgcn_mfma_f32_16x16x32_bf16(afrag, bfrag, acc[j], 0, 0, 0);
            }
        }
    }

    // Epilogue: C/D layout col = lane&15, row = (lane>>4)*4 + reg (verified m89/m91)
    float* gp = g_part + ((size_t)kz << 18);
    const int col = lane & 15;
    const int rq  = (lane >> 4) * 4;
#pragma unroll
    for (int j = 0; j < 4; ++j) {
#pragma unroll
        for (int reg = 0; reg < 4; ++reg) {
            const int rg = bm * 64 + w * 16 + rq + reg;
            const int cg = bn * 64 + j * 16 + col;
            gp[rg * CH + cg] = acc[j][reg];
        }
    }
}

// ---------------------------------------------------------------- reduce -----
// g_pad[row][0..767] = gscale * sum of 4 split-K slices; cols 512..767 duplicate
// cols 0..255 so the loss kernel can read (i+b)%512 as ONE contiguous float4.
__global__ __launch_bounds__(256) void reduce_pad_kernel(const float* __restrict__ g_part,
                                                         float* __restrict__ g_pad) {
    const float gscale = 1.0f / 1048576.0f;          // 1/(b*local_ch*w*h)
    int t = blockIdx.x * 256 + threadIdx.x;          // 0..65535
    const float4* p = (const float4*)g_part;
    float4 s = p[t];
#pragma unroll
    for (int sl = 1; sl < SPLITK; ++sl) {
        float4 v = p[t + sl * 65536];
        s.x += v.x; s.y += v.y; s.z += v.z; s.w += v.w;
    }
    s.x *= gscale; s.y *= gscale; s.z *= gscale; s.w *= gscale;
    const int row = t >> 7;                          // 128 float4 per row
    const int c4  = t & 127;
    float4* dst = (float4*)(g_pad + (size_t)row * GPAD);
    dst[c4] = s;
    if (c4 < 64) dst[c4 + 128] = s;                  // duplicate cols 0..255
}

// ---------------------------------------------------------------- loss -------
// Block partial -> plain store to partials[blk]. 2048 blocks, i = blk>>2.
// g-read is now ONE 16B load per (j,k): g_pad[row*768 + i + 4*lane .. +3]
// (4B-aligned only when i%4==0; gfx950 handles unaligned dwordx4, and a
// compiler split back to dwords merely reproduces the old pattern).
__global__ __launch_bounds__(256) void loss_kernel(const float* __restrict__ target,
                                                   const float* __restrict__ g_pad,
                                                   float* __restrict__ partials) {
    const float lscale = 1.0e6f / 33554432.0f;       // WEIGHT / count

    const int tid  = threadIdx.x;
    const int lane = tid & 63;
    const int wv   = tid >> 6;
    const int blk  = blockIdx.x;
    const int i    = blk >> 2;                       // 4 blocks per i

    const float4* t4 = (const float4*)target;
    const float* gbase = g_pad + i + 4 * lane;       // column start, per thread
    float acc = 0.0f;

#pragma unroll
    for (int j = 0; j < 4; ++j) {
        float4 tv[4];
        float4 gv[4];
#pragma unroll
        for (int k = 0; k < 4; ++k) {
            const int idx4 = blk * 4096 + j * 1024 + k * 256 + tid;
            tv[k] = t4[idx4];
            const int a   = (blk & 3) * 64 + j * 16 + k * 4 + wv;   // = (idx4>>6)&255
            const int row = (i + a) & 511;
            __builtin_memcpy(&gv[k], gbase + (size_t)row * GPAD, sizeof(float4));
        }
#pragma unroll
        for (int k = 0; k < 4; ++k) {
            float d0 = gv[k].x - tv[k].x;
            float d1 = gv[k].y - tv[k].y;
            float d2 = gv[k].z - tv[k].z;
            float d3 = gv[k].w - tv[k].w;
            acc += d0 * d0 + d1 * d1 + d2 * d2 + d3 * d3;
        }
    }

    // wave reduce, then cross-wave via LDS, ONE plain store per block (no atomics)
#pragma unroll
    for (int off = 32; off > 0; off >>= 1) acc += __shfl_xor(acc, off, 64);
    __shared__ float wsum[4];
    if (lane == 0) wsum[wv] = acc;
    __syncthreads();
    if (tid == 0)
        partials[blk] = (wsum[0] + wsum[1] + wsum[2] + wsum[3]) * lscale;
}

// ---------------------------------------------------------------- finish -----
// Sum 2048 partials in one block; plain store to out (no memset needed).
__global__ __launch_bounds__(256) void finish_kernel(const float* __restrict__ partials,
                                                     float* __restrict__ out) {
    const int tid  = threadIdx.x;
    const int lane = tid & 63;
    const int wv   = tid >> 6;
    const float4* p = (const float4*)partials;       // 512 float4
    float4 a = p[tid], b = p[tid + 256];
    float s = a.x + a.y + a.z + a.w + b.x + b.y + b.z + b.w;
#pragma unroll
    for (int off = 32; off > 0; off >>= 1) s += __shfl_xor(s, off, 64);
    __shared__ float wsum[4];
    if (lane == 0) wsum[wv] = s;
    __syncthreads();
    if (tid == 0) out[0] = wsum[0] + wsum[1] + wsum[2] + wsum[3];
}

// ---------------------------------------------------------------- launch -----
extern "C" void kernel_launch(void* const* d_in, const int* in_sizes, int n_in,
                              void* d_out, int out_size, void* d_ws, size_t ws_size,
                              hipStream_t stream) {
    const float* x      = (const float*)d_in[0];   // 2097152 fp32
    const float* target = (const float*)d_in[1];   // 33554432 fp32
    float* out = (float*)d_out;

    __hip_bfloat16* feats = (__hip_bfloat16*)d_ws;                        // 4 MB
    float* g_part   = (float*)((char*)d_ws + FEATS_ELEMS * sizeof(__hip_bfloat16)); // 4 MB
    float* g_pad    = g_part + SPLITK * CH * CH;                          // 1.5 MB
    float* partials = g_pad + CH * GPAD;                                  // 8 KB

    convert_kernel<<<FEATS_ELEMS / (256 * 8), 256, 0, stream>>>(x, feats);
    gemm_kernel<<<dim3(CH / BM, CH / BM, SPLITK), 256, 0, stream>>>(feats, g_part);
    reduce_pad_kernel<<<CH * CH / 4 / 256, 256, 0, stream>>>(g_part, g_pad);
    loss_kernel<<<LOSS_BLOCKS, 256, 0, stream>>>(target, g_pad, partials);
    finish_kernel<<<1, 256, 0, stream>>>(partials, out);
}